// Round 5
// baseline (204.724 us; speedup 1.0000x reference)
//
#include <hip/hip_runtime.h>
#include <hip/hip_bf16.h>

// SelfAttention: B=2, S=2048, H=16, D=64, E=1024
// ROUND 5: proj/outproj byte-exact R0 (best measured). attn = R0 body with
// TWO changes backed by R3/R4 evidence:
//   1. K fragments read DIRECT from global (L1-hot 8KB tile, R3 proved
//      L2-residency) instead of LDS-staged -> K traffic moves to the vector
//      -memory pipe, parallel to LDS. LDS pipe load per block-tile ~halves
//      (V staging + V reads only); wave count / barriers / MFMA shape all
//      unchanged (R4 proved concurrency must not drop).
//   2. XCD-swizzled block decode (R3: FETCH 69.7->12.4MB, time-neutral).
//   + s_setprio(1) around MFMA clusters (T5, measured +4-7% on attn).
// ws: Qb[0,8M) Kb[8M,16M) Vt[16M,24M) Og[24M,32M).

#define NHB 16
#define HS  64
#define EMB 1024
#define BB  2
#define SS  2048
#define NT  (SS / 64)

typedef __bf16 bf16_t;
typedef bf16_t bf16x8 __attribute__((ext_vector_type(8)));
typedef bf16_t bf16x4 __attribute__((ext_vector_type(4)));
typedef float  f32x4  __attribute__((ext_vector_type(4)));

__device__ __forceinline__ f32x4 mfma16(bf16x8 a, bf16x8 b, f32x4 c) {
    return __builtin_amdgcn_mfma_f32_16x16x32_bf16(a, b, c, 0, 0, 0);
}

// raw v_exp_f32 (computes 2^x) -- NOT libm exp2f (slow guarded sequence)
__device__ __forceinline__ float fast_exp2(float x) {
#if __has_builtin(__builtin_amdgcn_exp2f)
    return __builtin_amdgcn_exp2f(x);
#else
    float r;
    asm("v_exp_f32 %0, %1" : "=v"(r) : "v"(x));
    return r;
#endif
}

// ---------------------------------------------------------------------------
// Kernel 1: Q/K/V projections — byte-identical to R0 (measured-best config).
// ---------------------------------------------------------------------------
__global__ __launch_bounds__(512) void proj_kernel(
    const float* __restrict__ queries, const float* __restrict__ keys,
    const float* __restrict__ values,
    const float* __restrict__ Wq, const float* __restrict__ Wk,
    const float* __restrict__ Wv,
    bf16_t* __restrict__ Qb, bf16_t* __restrict__ Kb, bf16_t* __restrict__ Vt)
{
    __shared__ bf16_t Ws[3][64][72];
    __shared__ bf16_t Xs[128][72];

    const int tid  = threadIdx.x;
    const int wave = tid >> 6, lane = tid & 63;
    const int q4 = lane >> 4, l16 = lane & 15;
    const int s0 = blockIdx.x * 128;
    const int h  = blockIdx.y, n = blockIdx.z;

    #pragma unroll
    for (int i = 0; i < 6; ++i) {
        int g = i * 512 + tid;
        int mW = g >> 10;                 // uniform per i
        int idx4 = g & 1023;
        const float* wp = (mW == 0) ? Wq : (mW == 1) ? Wk : Wv;
        float4 v = ((const float4*)wp)[idx4];
        int r = idx4 >> 4, c = (idx4 & 15) * 4;
        Ws[mW][r][c+0] = (bf16_t)v.x; Ws[mW][r][c+1] = (bf16_t)v.y;
        Ws[mW][r][c+2] = (bf16_t)v.z; Ws[mW][r][c+3] = (bf16_t)v.w;
    }

    const size_t headBase = (size_t)(n * NHB + h) * SS * HS;

    float4 gx[4];
    auto loadX = [&](const float* xp) {
        #pragma unroll
        for (int i = 0; i < 4; ++i) {
            int idx4 = i * 512 + tid;                 // 2048 chunks: 128 x 16
            int r = idx4 >> 4, c = (idx4 & 15) * 4;
            gx[i] = *(const float4*)&xp[((size_t)(n * SS + s0 + r)) * EMB + h * HS + c];
        }
    };
    loadX(queries);

    for (int p = 0; p < 3; ++p) {
        __syncthreads();
        #pragma unroll
        for (int i = 0; i < 4; ++i) {
            int idx4 = i * 512 + tid;
            int r = idx4 >> 4, c = (idx4 & 15) * 4;
            Xs[r][c+0] = (bf16_t)gx[i].x; Xs[r][c+1] = (bf16_t)gx[i].y;
            Xs[r][c+2] = (bf16_t)gx[i].z; Xs[r][c+3] = (bf16_t)gx[i].w;
        }
        if (p == 0) loadX(keys);
        else if (p == 1) loadX(values);
        __syncthreads();

        bf16x8 xf[2], wf[4][2];
        #pragma unroll
        for (int kk = 0; kk < 2; ++kk)
            xf[kk] = *(const bf16x8*)&Xs[wave * 16 + l16][kk * 32 + q4 * 8];
        #pragma unroll
        for (int ct = 0; ct < 4; ++ct)
            #pragma unroll
            for (int kk = 0; kk < 2; ++kk)
                wf[ct][kk] = *(const bf16x8*)&Ws[p][ct * 16 + l16][kk * 32 + q4 * 8];

        if (p < 2) {
            // sigma gather: phys channel = q4*16 + ct*4 + i -> two 16B stores
            bf16_t* dst = (p == 0) ? Qb : Kb;
            // Q carries log2e/sqrt(EMB) so attn can use raw v_exp_f32 (2^x)
            const float sc = (p == 0) ? (0.03125f * 1.44269504f) : 1.0f;
            bf16x8 lo, hi;
            #pragma unroll
            for (int ct = 0; ct < 4; ++ct) {
                f32x4 acc = {};
                acc = mfma16(wf[ct][0], xf[0], acc);
                acc = mfma16(wf[ct][1], xf[1], acc);
                #pragma unroll
                for (int i = 0; i < 4; ++i) {
                    bf16_t v = (bf16_t)(acc[i] * sc);
                    if (ct < 2) lo[ct * 4 + i] = v;
                    else        hi[(ct - 2) * 4 + i] = v;
                }
            }
            bf16_t* rp = dst + headBase
                + (size_t)(s0 + wave * 16 + l16) * HS + q4 * 16;
            *(bf16x8*)rp = lo;
            *(bf16x8*)(rp + 8) = hi;
        } else {
            #pragma unroll
            for (int ct = 0; ct < 4; ++ct) {
                f32x4 acc = {};
                acc = mfma16(xf[0], wf[ct][0], acc);
                acc = mfma16(xf[1], wf[ct][1], acc);
                bf16x4 pk;
                #pragma unroll
                for (int i = 0; i < 4; ++i) pk[i] = (bf16_t)acc[i];
                *(bf16x4*)&Vt[headBase + (size_t)(ct * 16 + l16) * SS
                              + s0 + (wave >> 1) * 32 + q4 * 8 + (wave & 1) * 4] = pk;
            }
        }
    }
}

// ---------------------------------------------------------------------------
// Kernel 2: flash attention. grid 512 (XCD-swizzled) x 512 threads.
// R0 body; K fragments now read direct from global (L1-hot 8KB tile shared
// by all 8 waves) -- Ks staging deleted, V staging/dbuf/barriers unchanged.
// ---------------------------------------------------------------------------
__global__ __launch_bounds__(512) void attn_kernel(
    const bf16_t* __restrict__ Qb, const bf16_t* __restrict__ Kb,
    const bf16_t* __restrict__ Vt, const int* __restrict__ mask,
    bf16_t* __restrict__ Og)
{
    __shared__ __align__(16) unsigned char smem[34816];
    auto Vs = (bf16_t(*)[64][72])(smem);            // [2][d][kappa-key] 18432B
    auto Ms = (float(*)[64])(smem + 18432);         // [2][64] additive bias
    float* fbuf = (float*)smem;                      // combine: 32 KB
    float* lbuf = (float*)(smem + 32768);            // combine: 2 KB

    const int tid = threadIdx.x;
    const int w = tid >> 6, lane = tid & 63;
    const int q4 = lane >> 4, l16 = lane & 15;
    const int wq = w & 3, wk = w >> 2;

    // XCD swizzle: all 16 q-tiles of a head share an XCD (id%8).
    const int bid = blockIdx.x;
    const int r = bid & 7, t = bid >> 3;
    const int gi = t >> 4, qt = t & 15;
    const int g = gi * 8 + r;
    const int h = g & 15, n = g >> 4;

    const size_t headBase = (size_t)(n * NHB + h) * SS * HS;
    const int* mrow = mask + n * SS;

    const int sr = tid >> 3, sc = (tid & 7) * 8;
    const bf16_t* vt_src = Vt + headBase + (size_t)sr * SS + sc;
    // per-lane direct K fragment base: row = ct*16+l16 of tile, col = q4*8
    const bf16_t* kb_frag = Kb + headBase + (size_t)l16 * HS + q4 * 8;

    bf16x8 bq[2][2];
    #pragma unroll
    for (int st = 0; st < 2; ++st) {
        const bf16_t* qptr = Qb + headBase
            + (size_t)(qt * 128 + wq * 32 + st * 16 + l16) * HS;
        bq[st][0] = *(const bf16x8*)&qptr[q4 * 8];
        bq[st][1] = *(const bf16x8*)&qptr[32 + q4 * 8];
    }

    bf16x8 ones;
    #pragma unroll
    for (int i = 0; i < 8; ++i) ones[i] = (bf16_t)1.0f;

    f32x4 oaccT[2][4] = {};
    f32x4 lacc[2] = {};

    *(bf16x8*)&Vs[0][sr][sc] = *(const bf16x8*)vt_src;
    if (tid < 64) Ms[0][tid] = mrow[tid] ? 0.0f : -3e38f;
    __syncthreads();

    for (int kt = 0; kt < NT; ++kt) {
        const int cur = kt & 1;
        const bool has_next = (kt + 1) < NT;
        const int k0 = kt * 64;
        bf16x8 gv; float gm = 0.f;
        if (has_next) {
            const int k0n = k0 + 64;
            gv = *(const bf16x8*)(vt_src + k0n);
            if (tid < 64) gm = mrow[k0n + tid] ? 0.0f : -3e38f;
        }

        // current-tile K fragments, direct from global (L1-hot tile)
        bf16x8 ak[2][2];
        #pragma unroll
        for (int c2 = 0; c2 < 2; ++c2) {
            const int ct = wk * 2 + c2;
            const bf16_t* kp = kb_frag + (size_t)(k0 + ct * 16) * HS;
            ak[c2][0] = *(const bf16x8*)kp;
            ak[c2][1] = *(const bf16x8*)(kp + 32);
        }

        // S^T = bias + K.Q^T over this wave's 32-key half
        f32x4 sacc[2][2];
        __builtin_amdgcn_s_setprio(1);
        #pragma unroll
        for (int c2 = 0; c2 < 2; ++c2) {
            const int ct = wk * 2 + c2;
            float4 bias = *(const float4*)&Ms[cur][ct * 16 + q4 * 4];
            f32x4 b4 = {bias.x, bias.y, bias.z, bias.w};
            #pragma unroll
            for (int st = 0; st < 2; ++st) {
                f32x4 s = mfma16(ak[c2][0], bq[st][0], b4);
                sacc[st][c2] = mfma16(ak[c2][1], bq[st][1], s);
            }
        }
        __builtin_amdgcn_s_setprio(0);

        // P = 2^S (Q carries log2e/32): one v_exp_f32 per element, no mul
        bf16x4 pv[2][2];
        #pragma unroll
        for (int c2 = 0; c2 < 2; ++c2)
            #pragma unroll
            for (int st = 0; st < 2; ++st) {
                bf16x4 pk;
                #pragma unroll
                for (int j = 0; j < 4; ++j)
                    pk[j] = (bf16_t)fast_exp2(sacc[st][c2][j]);
                pv[st][c2] = pk;
            }

        // O^T += V^T.P^T ; lsum += ones.P^T
        bf16x8 pa[2];
        #pragma unroll
        for (int st = 0; st < 2; ++st)
            pa[st] = __builtin_shufflevector(pv[st][0], pv[st][1],
                                             0, 1, 2, 3, 4, 5, 6, 7);
        __builtin_amdgcn_s_setprio(1);
        #pragma unroll
        for (int dt = 0; dt < 4; ++dt) {
            bf16x8 av = *(const bf16x8*)&Vs[cur][dt * 16 + l16][wk * 32 + q4 * 8];
            oaccT[0][dt] = mfma16(av, pa[0], oaccT[0][dt]);
            oaccT[1][dt] = mfma16(av, pa[1], oaccT[1][dt]);
        }
        lacc[0] = mfma16(ones, pa[0], lacc[0]);
        lacc[1] = mfma16(ones, pa[1], lacc[1]);
        __builtin_amdgcn_s_setprio(0);

        if (has_next) {
            const int nxt = 1 - cur;
            *(bf16x8*)&Vs[nxt][sr][sc] = gv;
            if (tid < 64) Ms[nxt][tid] = gm;
        }
        __syncthreads();
    }

    float ls[2] = {lacc[0][0], lacc[1][0]};

    // combine partner halves: waves 4-7 publish, waves 0-3 reduce + store
    if (w >= 4) {
        const int lanecol = wq * 64 + lane;
        #pragma unroll
        for (int st = 0; st < 2; ++st) {
            #pragma unroll
            for (int dt = 0; dt < 4; ++dt)
                #pragma unroll
                for (int j = 0; j < 4; ++j)
                    fbuf[(st * 16 + dt * 4 + j) * 256 + lanecol] = oaccT[st][dt][j];
            lbuf[st * 256 + lanecol] = ls[st];
        }
    }
    __syncthreads();
    if (w < 4) {
        const int lanecol = wq * 64 + lane;
        #pragma unroll
        for (int st = 0; st < 2; ++st) {
            #pragma unroll
            for (int dt = 0; dt < 4; ++dt)
                #pragma unroll
                for (int j = 0; j < 4; ++j)
                    oaccT[st][dt][j] += fbuf[(st * 16 + dt * 4 + j) * 256 + lanecol];
            ls[st] += lbuf[st * 256 + lanecol];
        }
        #pragma unroll
        for (int st = 0; st < 2; ++st) {
            const float inv = 1.f / ls[st];
            const int qrow = qt * 128 + wq * 32 + st * 16 + l16;
            bf16_t* obase = Og + ((size_t)(n * SS + qrow)) * EMB + h * HS;
            #pragma unroll
            for (int dt = 0; dt < 4; ++dt) {
                bf16x4 ov;
                #pragma unroll
                for (int j = 0; j < 4; ++j) ov[j] = (bf16_t)(oaccT[st][dt][j] * inv);
                *(bf16x4*)&obase[dt * 16 + q4 * 4] = ov;
            }
        }
    }
}

// ---------------------------------------------------------------------------
// Kernel 3: out = Og @ Wout.T + bout — byte-identical to R0 (measured-best).
// ---------------------------------------------------------------------------
__global__ __launch_bounds__(512) void outproj_kernel(
    const bf16_t* __restrict__ Og, const float* __restrict__ Wout,
    const float* __restrict__ bout, float* __restrict__ out)
{
    __shared__ bf16_t As[2][128][72];
    __shared__ bf16_t Bs[2][64][72];
    const int tid = threadIdx.x;
    const int w = tid >> 6, lane = tid & 63;
    const int q4 = lane >> 4, l16 = lane & 15;
    const int wr = w >> 1, wc = w & 1;
    const int t0 = blockIdx.x * 128, c0 = blockIdx.y * 64;

    const int sr0 = tid >> 3, sc0 = (tid & 7) * 8;
    const int sr1 = sr0 + 64;
    const bf16_t* a0 = Og + (size_t)(t0 + sr0) * EMB + sc0;
    const bf16_t* a1 = Og + (size_t)(t0 + sr1) * EMB + sc0;
    const float*  b0 = Wout + (size_t)(c0 + sr0) * EMB + sc0;

    auto cvt8 = [](float4 x, float4 y) {
        bf16x8 r;
        r[0] = (bf16_t)x.x; r[1] = (bf16_t)x.y; r[2] = (bf16_t)x.z; r[3] = (bf16_t)x.w;
        r[4] = (bf16_t)y.x; r[5] = (bf16_t)y.y; r[6] = (bf16_t)y.z; r[7] = (bf16_t)y.w;
        return r;
    };

    f32x4 acc[2][2] = {};

    *(bf16x8*)&As[0][sr0][sc0] = *(const bf16x8*)a0;
    *(bf16x8*)&As[0][sr1][sc0] = *(const bf16x8*)a1;
    *(bf16x8*)&Bs[0][sr0][sc0] = cvt8(*(const float4*)b0, *(const float4*)(b0 + 4));
    __syncthreads();

    const int NE = EMB / 64;
    for (int et = 0; et < NE; ++et) {
        const int cur = et & 1;
        const bool has_next = (et + 1) < NE;
        bf16x8 ga0, ga1; float4 gb0, gb1;
        if (has_next) {
            const int e0 = (et + 1) * 64;
            ga0 = *(const bf16x8*)(a0 + e0); ga1 = *(const bf16x8*)(a1 + e0);
            gb0 = *(const float4*)(b0 + e0); gb1 = *(const float4*)(b0 + e0 + 4);
        }

        bf16x8 af[2][2], bfr[2][2];
        #pragma unroll
        for (int st = 0; st < 2; ++st)
            #pragma unroll
            for (int kk = 0; kk < 2; ++kk)
                af[st][kk] = *(const bf16x8*)&As[cur][wr * 32 + st * 16 + l16][kk * 32 + q4 * 8];
        #pragma unroll
        for (int ct = 0; ct < 2; ++ct)
            #pragma unroll
            for (int kk = 0; kk < 2; ++kk)
                bfr[ct][kk] = *(const bf16x8*)&Bs[cur][wc * 32 + ct * 16 + l16][kk * 32 + q4 * 8];
        #pragma unroll
        for (int st = 0; st < 2; ++st)
            #pragma unroll
            for (int ct = 0; ct < 2; ++ct) {
                acc[st][ct] = mfma16(af[st][0], bfr[ct][0], acc[st][ct]);
                acc[st][ct] = mfma16(af[st][1], bfr[ct][1], acc[st][ct]);
            }

        if (has_next) {
            const int nxt = 1 - cur;
            *(bf16x8*)&As[nxt][sr0][sc0] = ga0;
            *(bf16x8*)&As[nxt][sr1][sc0] = ga1;
            *(bf16x8*)&Bs[nxt][sr0][sc0] = cvt8(gb0, gb1);
        }
        __syncthreads();
    }

    #pragma unroll
    for (int ct = 0; ct < 2; ++ct) {
        const int c = c0 + wc * 32 + ct * 16 + l16;
        const float bias = bout[c];
        #pragma unroll
        for (int st = 0; st < 2; ++st)
            #pragma unroll
            for (int i = 0; i < 4; ++i)
                out[(size_t)(t0 + wr * 32 + st * 16 + q4 * 4 + i) * EMB + c]
                    = acc[st][ct][i] + bias;
    }
}

extern "C" void kernel_launch(void* const* d_in, const int* in_sizes, int n_in,
                              void* d_out, int out_size, void* d_ws, size_t ws_size,
                              hipStream_t stream)
{
    const float* values  = (const float*)d_in[0];
    const float* keys    = (const float*)d_in[1];
    const float* queries = (const float*)d_in[2];
    const int*   mask    = (const int*)d_in[3];
    const float* Wq      = (const float*)d_in[4];
    const float* Wk      = (const float*)d_in[5];
    const float* Wv      = (const float*)d_in[6];
    const float* Wout    = (const float*)d_in[7];
    const float* bout    = (const float*)d_in[8];
    float* out = (float*)d_out;

    const size_t M8 = 8ull * 1024 * 1024;
    bf16_t* Qb = (bf16_t*)d_ws;
    bf16_t* Kb = (bf16_t*)((char*)d_ws + 1 * M8);
    bf16_t* Vt = (bf16_t*)((char*)d_ws + 2 * M8);
    bf16_t* Og = (bf16_t*)((char*)d_ws + 3 * M8);

    proj_kernel<<<dim3(SS / 128, NHB, BB), 512, 0, stream>>>(
        queries, keys, values, Wq, Wk, Wv, Qb, Kb, Vt);
    attn_kernel<<<dim3(512), 512, 0, stream>>>(
        Qb, Kb, Vt, mask, Og);
    outproj_kernel<<<dim3((BB * SS) / 128, EMB / 64), 512, 0, stream>>>(
        Og, Wout, bout, out);
}

// Round 6
// 199.368 us; speedup vs baseline: 1.0269x; 1.0269x over previous
//
#include <hip/hip_runtime.h>
#include <hip/hip_bf16.h>

// SelfAttention: B=2, S=2048, H=16, D=64, E=1024
// ROUND 6: proj/outproj byte-exact R0 (best measured). attn = R0 body with
// K moved out of LDS onto the vmem pipe -- but unlike R5 (which exposed vmem
// latency serially, 81us), K fragments are REGISTER-PREFETCHED one tile ahead
// (issued with gv at loop top, consumed next iteration after the barrier).
// LDS per block-tile ~halves (K stage-write + K reads gone); V path, barriers,
// MFMA shapes, combine all unchanged. XCD swizzle kept (R3: FETCH 69.7->12.4MB,
// time-neutral). setprio kept.
// ws: Qb[0,8M) Kb[8M,16M) Vt[16M,24M) Og[24M,32M).

#define NHB 16
#define HS  64
#define EMB 1024
#define BB  2
#define SS  2048
#define NT  (SS / 64)

typedef __bf16 bf16_t;
typedef bf16_t bf16x8 __attribute__((ext_vector_type(8)));
typedef bf16_t bf16x4 __attribute__((ext_vector_type(4)));
typedef float  f32x4  __attribute__((ext_vector_type(4)));

__device__ __forceinline__ f32x4 mfma16(bf16x8 a, bf16x8 b, f32x4 c) {
    return __builtin_amdgcn_mfma_f32_16x16x32_bf16(a, b, c, 0, 0, 0);
}

// raw v_exp_f32 (computes 2^x) -- NOT libm exp2f (slow guarded sequence)
__device__ __forceinline__ float fast_exp2(float x) {
#if __has_builtin(__builtin_amdgcn_exp2f)
    return __builtin_amdgcn_exp2f(x);
#else
    float r;
    asm("v_exp_f32 %0, %1" : "=v"(r) : "v"(x));
    return r;
#endif
}

// ---------------------------------------------------------------------------
// Kernel 1: Q/K/V projections — byte-identical to R0 (measured-best config).
// ---------------------------------------------------------------------------
__global__ __launch_bounds__(512) void proj_kernel(
    const float* __restrict__ queries, const float* __restrict__ keys,
    const float* __restrict__ values,
    const float* __restrict__ Wq, const float* __restrict__ Wk,
    const float* __restrict__ Wv,
    bf16_t* __restrict__ Qb, bf16_t* __restrict__ Kb, bf16_t* __restrict__ Vt)
{
    __shared__ bf16_t Ws[3][64][72];
    __shared__ bf16_t Xs[128][72];

    const int tid  = threadIdx.x;
    const int wave = tid >> 6, lane = tid & 63;
    const int q4 = lane >> 4, l16 = lane & 15;
    const int s0 = blockIdx.x * 128;
    const int h  = blockIdx.y, n = blockIdx.z;

    #pragma unroll
    for (int i = 0; i < 6; ++i) {
        int g = i * 512 + tid;
        int mW = g >> 10;                 // uniform per i
        int idx4 = g & 1023;
        const float* wp = (mW == 0) ? Wq : (mW == 1) ? Wk : Wv;
        float4 v = ((const float4*)wp)[idx4];
        int r = idx4 >> 4, c = (idx4 & 15) * 4;
        Ws[mW][r][c+0] = (bf16_t)v.x; Ws[mW][r][c+1] = (bf16_t)v.y;
        Ws[mW][r][c+2] = (bf16_t)v.z; Ws[mW][r][c+3] = (bf16_t)v.w;
    }

    const size_t headBase = (size_t)(n * NHB + h) * SS * HS;

    float4 gx[4];
    auto loadX = [&](const float* xp) {
        #pragma unroll
        for (int i = 0; i < 4; ++i) {
            int idx4 = i * 512 + tid;                 // 2048 chunks: 128 x 16
            int r = idx4 >> 4, c = (idx4 & 15) * 4;
            gx[i] = *(const float4*)&xp[((size_t)(n * SS + s0 + r)) * EMB + h * HS + c];
        }
    };
    loadX(queries);

    for (int p = 0; p < 3; ++p) {
        __syncthreads();
        #pragma unroll
        for (int i = 0; i < 4; ++i) {
            int idx4 = i * 512 + tid;
            int r = idx4 >> 4, c = (idx4 & 15) * 4;
            Xs[r][c+0] = (bf16_t)gx[i].x; Xs[r][c+1] = (bf16_t)gx[i].y;
            Xs[r][c+2] = (bf16_t)gx[i].z; Xs[r][c+3] = (bf16_t)gx[i].w;
        }
        if (p == 0) loadX(keys);
        else if (p == 1) loadX(values);
        __syncthreads();

        bf16x8 xf[2], wf[4][2];
        #pragma unroll
        for (int kk = 0; kk < 2; ++kk)
            xf[kk] = *(const bf16x8*)&Xs[wave * 16 + l16][kk * 32 + q4 * 8];
        #pragma unroll
        for (int ct = 0; ct < 4; ++ct)
            #pragma unroll
            for (int kk = 0; kk < 2; ++kk)
                wf[ct][kk] = *(const bf16x8*)&Ws[p][ct * 16 + l16][kk * 32 + q4 * 8];

        if (p < 2) {
            // sigma gather: phys channel = q4*16 + ct*4 + i -> two 16B stores
            bf16_t* dst = (p == 0) ? Qb : Kb;
            // Q carries log2e/sqrt(EMB) so attn can use raw v_exp_f32 (2^x)
            const float sc = (p == 0) ? (0.03125f * 1.44269504f) : 1.0f;
            bf16x8 lo, hi;
            #pragma unroll
            for (int ct = 0; ct < 4; ++ct) {
                f32x4 acc = {};
                acc = mfma16(wf[ct][0], xf[0], acc);
                acc = mfma16(wf[ct][1], xf[1], acc);
                #pragma unroll
                for (int i = 0; i < 4; ++i) {
                    bf16_t v = (bf16_t)(acc[i] * sc);
                    if (ct < 2) lo[ct * 4 + i] = v;
                    else        hi[(ct - 2) * 4 + i] = v;
                }
            }
            bf16_t* rp = dst + headBase
                + (size_t)(s0 + wave * 16 + l16) * HS + q4 * 16;
            *(bf16x8*)rp = lo;
            *(bf16x8*)(rp + 8) = hi;
        } else {
            #pragma unroll
            for (int ct = 0; ct < 4; ++ct) {
                f32x4 acc = {};
                acc = mfma16(xf[0], wf[ct][0], acc);
                acc = mfma16(xf[1], wf[ct][1], acc);
                bf16x4 pk;
                #pragma unroll
                for (int i = 0; i < 4; ++i) pk[i] = (bf16_t)acc[i];
                *(bf16x4*)&Vt[headBase + (size_t)(ct * 16 + l16) * SS
                              + s0 + (wave >> 1) * 32 + q4 * 8 + (wave & 1) * 4] = pk;
            }
        }
    }
}

// ---------------------------------------------------------------------------
// Kernel 2: flash attention. grid 512 (XCD-swizzled) x 512 threads.
// R0 body; K fragments register-prefetched direct from global one tile ahead
// (issued with gv, consumed next iter) -- Ks LDS staging deleted. V staging,
// double-buffer, barriers, MFMA shapes, combine: unchanged.
// ---------------------------------------------------------------------------
__global__ __launch_bounds__(512) void attn_kernel(
    const bf16_t* __restrict__ Qb, const bf16_t* __restrict__ Kb,
    const bf16_t* __restrict__ Vt, const int* __restrict__ mask,
    bf16_t* __restrict__ Og)
{
    __shared__ __align__(16) unsigned char smem[34816];
    auto Vs = (bf16_t(*)[64][72])(smem);            // [2][d][kappa-key] 18432B
    auto Ms = (float(*)[64])(smem + 18432);         // [2][64] additive bias
    float* fbuf = (float*)smem;                      // combine: 32 KB
    float* lbuf = (float*)(smem + 32768);            // combine: 2 KB

    const int tid = threadIdx.x;
    const int w = tid >> 6, lane = tid & 63;
    const int q4 = lane >> 4, l16 = lane & 15;
    const int wq = w & 3, wk = w >> 2;

    // XCD swizzle: all 16 q-tiles of a head share an XCD (id%8).
    const int bid = blockIdx.x;
    const int r = bid & 7, t = bid >> 3;
    const int gi = t >> 4, qt = t & 15;
    const int g = gi * 8 + r;
    const int h = g & 15, n = g >> 4;

    const size_t headBase = (size_t)(n * NHB + h) * SS * HS;
    const int* mrow = mask + n * SS;

    const int sr = tid >> 3, sc = (tid & 7) * 8;
    const bf16_t* vt_src = Vt + headBase + (size_t)sr * SS + sc;
    // per-lane K fragment bases for this wave's two 16-key row groups
    const bf16_t* kp0 = Kb + headBase + (size_t)(wk * 32 + l16) * HS + q4 * 8;
    const bf16_t* kp1 = Kb + headBase + (size_t)(wk * 32 + 16 + l16) * HS + q4 * 8;

    bf16x8 bq[2][2];
    #pragma unroll
    for (int st = 0; st < 2; ++st) {
        const bf16_t* qptr = Qb + headBase
            + (size_t)(qt * 128 + wq * 32 + st * 16 + l16) * HS;
        bq[st][0] = *(const bf16x8*)&qptr[q4 * 8];
        bq[st][1] = *(const bf16x8*)&qptr[32 + q4 * 8];
    }

    bf16x8 ones;
    #pragma unroll
    for (int i = 0; i < 8; ++i) ones[i] = (bf16_t)1.0f;

    f32x4 oaccT[2][4] = {};
    f32x4 lacc[2] = {};

    // tile-0 prefetch: K -> registers, V -> LDS buf0, mask bias -> Ms[0]
    bf16x8 ak[2][2];
    ak[0][0] = *(const bf16x8*)kp0;  ak[0][1] = *(const bf16x8*)(kp0 + 32);
    ak[1][0] = *(const bf16x8*)kp1;  ak[1][1] = *(const bf16x8*)(kp1 + 32);
    *(bf16x8*)&Vs[0][sr][sc] = *(const bf16x8*)vt_src;
    if (tid < 64) Ms[0][tid] = mrow[tid] ? 0.0f : -3e38f;
    __syncthreads();

    const bf16_t* kn0 = kp0 + 64 * HS;
    const bf16_t* kn1 = kp1 + 64 * HS;

    for (int kt = 0; kt < NT; ++kt) {
        const int cur = kt & 1;
        const bool has_next = (kt + 1) < NT;
        bf16x8 gv, nk[2][2]; float gm = 0.f;
        if (has_next) {
            const int k0n = (kt + 1) * 64;
            gv = *(const bf16x8*)(vt_src + k0n);
            nk[0][0] = *(const bf16x8*)kn0;  nk[0][1] = *(const bf16x8*)(kn0 + 32);
            nk[1][0] = *(const bf16x8*)kn1;  nk[1][1] = *(const bf16x8*)(kn1 + 32);
            kn0 += 64 * HS; kn1 += 64 * HS;
            if (tid < 64) gm = mrow[k0n + tid] ? 0.0f : -3e38f;
        }

        // S^T = bias + K.Q^T over this wave's 32-key half (K in registers)
        f32x4 sacc[2][2];
        __builtin_amdgcn_s_setprio(1);
        #pragma unroll
        for (int c2 = 0; c2 < 2; ++c2) {
            const int ct = wk * 2 + c2;
            float4 bias = *(const float4*)&Ms[cur][ct * 16 + q4 * 4];
            f32x4 b4 = {bias.x, bias.y, bias.z, bias.w};
            #pragma unroll
            for (int st = 0; st < 2; ++st) {
                f32x4 s = mfma16(ak[c2][0], bq[st][0], b4);
                sacc[st][c2] = mfma16(ak[c2][1], bq[st][1], s);
            }
        }
        __builtin_amdgcn_s_setprio(0);

        // P = 2^S (Q carries log2e/32): one v_exp_f32 per element, no mul
        bf16x4 pv[2][2];
        #pragma unroll
        for (int c2 = 0; c2 < 2; ++c2)
            #pragma unroll
            for (int st = 0; st < 2; ++st) {
                bf16x4 pk;
                #pragma unroll
                for (int j = 0; j < 4; ++j)
                    pk[j] = (bf16_t)fast_exp2(sacc[st][c2][j]);
                pv[st][c2] = pk;
            }

        // O^T += V^T.P^T ; lsum += ones.P^T
        bf16x8 pa[2];
        #pragma unroll
        for (int st = 0; st < 2; ++st)
            pa[st] = __builtin_shufflevector(pv[st][0], pv[st][1],
                                             0, 1, 2, 3, 4, 5, 6, 7);
        __builtin_amdgcn_s_setprio(1);
        #pragma unroll
        for (int dt = 0; dt < 4; ++dt) {
            bf16x8 av = *(const bf16x8*)&Vs[cur][dt * 16 + l16][wk * 32 + q4 * 8];
            oaccT[0][dt] = mfma16(av, pa[0], oaccT[0][dt]);
            oaccT[1][dt] = mfma16(av, pa[1], oaccT[1][dt]);
        }
        lacc[0] = mfma16(ones, pa[0], lacc[0]);
        lacc[1] = mfma16(ones, pa[1], lacc[1]);
        __builtin_amdgcn_s_setprio(0);

        if (has_next) {
            const int nxt = 1 - cur;
            *(bf16x8*)&Vs[nxt][sr][sc] = gv;
            if (tid < 64) Ms[nxt][tid] = gm;
            ak[0][0] = nk[0][0]; ak[0][1] = nk[0][1];
            ak[1][0] = nk[1][0]; ak[1][1] = nk[1][1];
        }
        __syncthreads();
    }

    float ls[2] = {lacc[0][0], lacc[1][0]};

    // combine partner halves: waves 4-7 publish, waves 0-3 reduce + store
    if (w >= 4) {
        const int lanecol = wq * 64 + lane;
        #pragma unroll
        for (int st = 0; st < 2; ++st) {
            #pragma unroll
            for (int dt = 0; dt < 4; ++dt)
                #pragma unroll
                for (int j = 0; j < 4; ++j)
                    fbuf[(st * 16 + dt * 4 + j) * 256 + lanecol] = oaccT[st][dt][j];
            lbuf[st * 256 + lanecol] = ls[st];
        }
    }
    __syncthreads();
    if (w < 4) {
        const int lanecol = wq * 64 + lane;
        #pragma unroll
        for (int st = 0; st < 2; ++st) {
            #pragma unroll
            for (int dt = 0; dt < 4; ++dt)
                #pragma unroll
                for (int j = 0; j < 4; ++j)
                    oaccT[st][dt][j] += fbuf[(st * 16 + dt * 4 + j) * 256 + lanecol];
            ls[st] += lbuf[st * 256 + lanecol];
        }
        #pragma unroll
        for (int st = 0; st < 2; ++st) {
            const float inv = 1.f / ls[st];
            const int qrow = qt * 128 + wq * 32 + st * 16 + l16;
            bf16_t* obase = Og + ((size_t)(n * SS + qrow)) * EMB + h * HS;
            #pragma unroll
            for (int dt = 0; dt < 4; ++dt) {
                bf16x4 ov;
                #pragma unroll
                for (int j = 0; j < 4; ++j) ov[j] = (bf16_t)(oaccT[st][dt][j] * inv);
                *(bf16x4*)&obase[dt * 16 + q4 * 4] = ov;
            }
        }
    }
}

// ---------------------------------------------------------------------------
// Kernel 3: out = Og @ Wout.T + bout — byte-identical to R0 (measured-best).
// ---------------------------------------------------------------------------
__global__ __launch_bounds__(512) void outproj_kernel(
    const bf16_t* __restrict__ Og, const float* __restrict__ Wout,
    const float* __restrict__ bout, float* __restrict__ out)
{
    __shared__ bf16_t As[2][128][72];
    __shared__ bf16_t Bs[2][64][72];
    const int tid = threadIdx.x;
    const int w = tid >> 6, lane = tid & 63;
    const int q4 = lane >> 4, l16 = lane & 15;
    const int wr = w >> 1, wc = w & 1;
    const int t0 = blockIdx.x * 128, c0 = blockIdx.y * 64;

    const int sr0 = tid >> 3, sc0 = (tid & 7) * 8;
    const int sr1 = sr0 + 64;
    const bf16_t* a0 = Og + (size_t)(t0 + sr0) * EMB + sc0;
    const bf16_t* a1 = Og + (size_t)(t0 + sr1) * EMB + sc0;
    const float*  b0 = Wout + (size_t)(c0 + sr0) * EMB + sc0;

    auto cvt8 = [](float4 x, float4 y) {
        bf16x8 r;
        r[0] = (bf16_t)x.x; r[1] = (bf16_t)x.y; r[2] = (bf16_t)x.z; r[3] = (bf16_t)x.w;
        r[4] = (bf16_t)y.x; r[5] = (bf16_t)y.y; r[6] = (bf16_t)y.z; r[7] = (bf16_t)y.w;
        return r;
    };

    f32x4 acc[2][2] = {};

    *(bf16x8*)&As[0][sr0][sc0] = *(const bf16x8*)a0;
    *(bf16x8*)&As[0][sr1][sc0] = *(const bf16x8*)a1;
    *(bf16x8*)&Bs[0][sr0][sc0] = cvt8(*(const float4*)b0, *(const float4*)(b0 + 4));
    __syncthreads();

    const int NE = EMB / 64;
    for (int et = 0; et < NE; ++et) {
        const int cur = et & 1;
        const bool has_next = (et + 1) < NE;
        bf16x8 ga0, ga1; float4 gb0, gb1;
        if (has_next) {
            const int e0 = (et + 1) * 64;
            ga0 = *(const bf16x8*)(a0 + e0); ga1 = *(const bf16x8*)(a1 + e0);
            gb0 = *(const float4*)(b0 + e0); gb1 = *(const float4*)(b0 + e0 + 4);
        }

        bf16x8 af[2][2], bfr[2][2];
        #pragma unroll
        for (int st = 0; st < 2; ++st)
            #pragma unroll
            for (int kk = 0; kk < 2; ++kk)
                af[st][kk] = *(const bf16x8*)&As[cur][wr * 32 + st * 16 + l16][kk * 32 + q4 * 8];
        #pragma unroll
        for (int ct = 0; ct < 2; ++ct)
            #pragma unroll
            for (int kk = 0; kk < 2; ++kk)
                bfr[ct][kk] = *(const bf16x8*)&Bs[cur][wc * 32 + ct * 16 + l16][kk * 32 + q4 * 8];
        #pragma unroll
        for (int st = 0; st < 2; ++st)
            #pragma unroll
            for (int ct = 0; ct < 2; ++ct) {
                acc[st][ct] = mfma16(af[st][0], bfr[ct][0], acc[st][ct]);
                acc[st][ct] = mfma16(af[st][1], bfr[ct][1], acc[st][ct]);
            }

        if (has_next) {
            const int nxt = 1 - cur;
            *(bf16x8*)&As[nxt][sr0][sc0] = ga0;
            *(bf16x8*)&As[nxt][sr1][sc0] = ga1;
            *(bf16x8*)&Bs[nxt][sr0][sc0] = cvt8(gb0, gb1);
        }
        __syncthreads();
    }

    #pragma unroll
    for (int ct = 0; ct < 2; ++ct) {
        const int c = c0 + wc * 32 + ct * 16 + l16;
        const float bias = bout[c];
        #pragma unroll
        for (int st = 0; st < 2; ++st)
            #pragma unroll
            for (int i = 0; i < 4; ++i)
                out[(size_t)(t0 + wr * 32 + st * 16 + q4 * 4 + i) * EMB + c]
                    = acc[st][ct][i] + bias;
    }
}

extern "C" void kernel_launch(void* const* d_in, const int* in_sizes, int n_in,
                              void* d_out, int out_size, void* d_ws, size_t ws_size,
                              hipStream_t stream)
{
    const float* values  = (const float*)d_in[0];
    const float* keys    = (const float*)d_in[1];
    const float* queries = (const float*)d_in[2];
    const int*   mask    = (const int*)d_in[3];
    const float* Wq      = (const float*)d_in[4];
    const float* Wk      = (const float*)d_in[5];
    const float* Wv      = (const float*)d_in[6];
    const float* Wout    = (const float*)d_in[7];
    const float* bout    = (const float*)d_in[8];
    float* out = (float*)d_out;

    const size_t M8 = 8ull * 1024 * 1024;
    bf16_t* Qb = (bf16_t*)d_ws;
    bf16_t* Kb = (bf16_t*)((char*)d_ws + 1 * M8);
    bf16_t* Vt = (bf16_t*)((char*)d_ws + 2 * M8);
    bf16_t* Og = (bf16_t*)((char*)d_ws + 3 * M8);

    proj_kernel<<<dim3(SS / 128, NHB, BB), 512, 0, stream>>>(
        queries, keys, values, Wq, Wk, Wv, Qb, Kb, Vt);
    attn_kernel<<<dim3(512), 512, 0, stream>>>(
        Qb, Kb, Vt, mask, Og);
    outproj_kernel<<<dim3((BB * SS) / 128, EMB / 64), 512, 0, stream>>>(
        Og, Wout, bout, out);
}

// Round 7
// 171.005 us; speedup vs baseline: 1.1972x; 1.1659x over previous
//
#include <hip/hip_runtime.h>
#include <hip/hip_bf16.h>

// SelfAttention: B=2, S=2048, H=16, D=64, E=1024
// ROUND 7: clean single-variable test. attn + outproj are byte-exact R0
// (best measured: attn 43.9us). proj is R1's direct-load version (all 12
// X-fragment loads + 6 W loads issued up-front, no Xs LDS stage, ONE
// barrier) -- R1 proved it correct; R1's null total is now attributed to
// its simultaneous outproj occupancy regression (256 blocks = 1/CU).
// Theory: R0 proj is latency-bound (3 serialized load phases, ~1.8TB/s
// ~= 40us); upfront issue makes it BW-bound (~18us).
// ws: Qb[0,8M) Kb[8M,16M) Vt[16M,24M) Og[24M,32M).

#define NHB 16
#define HS  64
#define EMB 1024
#define BB  2
#define SS  2048
#define NT  (SS / 64)

typedef __bf16 bf16_t;
typedef bf16_t bf16x8 __attribute__((ext_vector_type(8)));
typedef bf16_t bf16x4 __attribute__((ext_vector_type(4)));
typedef float  f32x4  __attribute__((ext_vector_type(4)));

__device__ __forceinline__ f32x4 mfma16(bf16x8 a, bf16x8 b, f32x4 c) {
    return __builtin_amdgcn_mfma_f32_16x16x32_bf16(a, b, c, 0, 0, 0);
}

// raw v_exp_f32 (computes 2^x) -- NOT libm exp2f (slow guarded sequence)
__device__ __forceinline__ float fast_exp2(float x) {
#if __has_builtin(__builtin_amdgcn_exp2f)
    return __builtin_amdgcn_exp2f(x);
#else
    float r;
    asm("v_exp_f32 %0, %1" : "=v"(r) : "v"(x));
    return r;
#endif
}

__device__ __forceinline__ bf16x8 cvt8f(float4 x, float4 y) {
    bf16x8 r;
    r[0] = (bf16_t)x.x; r[1] = (bf16_t)x.y; r[2] = (bf16_t)x.z; r[3] = (bf16_t)x.w;
    r[4] = (bf16_t)y.x; r[5] = (bf16_t)y.y; r[6] = (bf16_t)y.z; r[7] = (bf16_t)y.w;
    return r;
}

// ---------------------------------------------------------------------------
// Kernel 1: Q/K/V projections (R1 version). grid (S/128, H, B), 512 threads.
// All 12 X-fragment loads + 6 W loads issued up-front; X never touches LDS
// (each lane's MFMA fragment is 2x 32B contiguous in global). One barrier.
// ---------------------------------------------------------------------------
__global__ __launch_bounds__(512, 4) void proj_kernel(
    const float* __restrict__ queries, const float* __restrict__ keys,
    const float* __restrict__ values,
    const float* __restrict__ Wq, const float* __restrict__ Wk,
    const float* __restrict__ Wv,
    bf16_t* __restrict__ Qb, bf16_t* __restrict__ Kb, bf16_t* __restrict__ Vt)
{
    __shared__ bf16_t Ws[3][64][72];

    const int tid  = threadIdx.x;
    const int wave = tid >> 6, lane = tid & 63;
    const int q4 = lane >> 4, l16 = lane & 15;
    const int s0 = blockIdx.x * 128;
    const int h  = blockIdx.y, n = blockIdx.z;

    // stage all three 64x64 weight matrices into LDS (fp32 -> bf16)
    #pragma unroll
    for (int i = 0; i < 6; ++i) {
        int g = i * 512 + tid;
        int mW = g >> 10;                 // uniform per i
        int idx4 = g & 1023;
        const float* wp = (mW == 0) ? Wq : (mW == 1) ? Wk : Wv;
        float4 v = ((const float4*)wp)[idx4];
        int r = idx4 >> 4, c = (idx4 & 15) * 4;
        Ws[mW][r][c+0] = (bf16_t)v.x; Ws[mW][r][c+1] = (bf16_t)v.y;
        Ws[mW][r][c+2] = (bf16_t)v.z; Ws[mW][r][c+3] = (bf16_t)v.w;
    }

    // direct per-lane fragment loads for Q, K, V (row = this lane's s-row,
    // channels kk*32 + q4*8 .. +7)
    const size_t xrow = (size_t)(n * SS + s0 + wave * 16 + l16) * EMB + h * HS;
    const float* xsrc[3] = {queries, keys, values};
    bf16x8 xb[3][2];
    #pragma unroll
    for (int p = 0; p < 3; ++p) {
        const float* rp = xsrc[p] + xrow;
        float4 t0 = *(const float4*)(rp + q4 * 8);
        float4 t1 = *(const float4*)(rp + q4 * 8 + 4);
        float4 t2 = *(const float4*)(rp + 32 + q4 * 8);
        float4 t3 = *(const float4*)(rp + 32 + q4 * 8 + 4);
        xb[p][0] = cvt8f(t0, t1);
        xb[p][1] = cvt8f(t2, t3);
    }

    __syncthreads();   // Ws ready

    const size_t headBase = (size_t)(n * NHB + h) * SS * HS;

    #pragma unroll
    for (int p = 0; p < 3; ++p) {
        bf16x8 wf[4][2];
        #pragma unroll
        for (int ct = 0; ct < 4; ++ct)
            #pragma unroll
            for (int kk = 0; kk < 2; ++kk)
                wf[ct][kk] = *(const bf16x8*)&Ws[p][ct * 16 + l16][kk * 32 + q4 * 8];

        if (p < 2) {
            // sigma gather: phys channel = q4*16 + ct*4 + i -> two 16B stores
            bf16_t* dst = (p == 0) ? Qb : Kb;
            // Q carries log2e/sqrt(EMB) so attn can use raw v_exp_f32 (2^x)
            const float sc = (p == 0) ? (0.03125f * 1.44269504f) : 1.0f;
            bf16x8 lo, hi;
            #pragma unroll
            for (int ct = 0; ct < 4; ++ct) {
                f32x4 acc = {};
                acc = mfma16(wf[ct][0], xb[p][0], acc);
                acc = mfma16(wf[ct][1], xb[p][1], acc);
                #pragma unroll
                for (int i = 0; i < 4; ++i) {
                    bf16_t v = (bf16_t)(acc[i] * sc);
                    if (ct < 2) lo[ct * 4 + i] = v;
                    else        hi[(ct - 2) * 4 + i] = v;
                }
            }
            bf16_t* rp = dst + headBase
                + (size_t)(s0 + wave * 16 + l16) * HS + q4 * 16;
            *(bf16x8*)rp = lo;
            *(bf16x8*)(rp + 8) = hi;
        } else {
            #pragma unroll
            for (int ct = 0; ct < 4; ++ct) {
                f32x4 acc = {};
                acc = mfma16(xb[2][0], wf[ct][0], acc);
                acc = mfma16(xb[2][1], wf[ct][1], acc);
                bf16x4 pk;
                #pragma unroll
                for (int i = 0; i < 4; ++i) pk[i] = (bf16_t)acc[i];
                *(bf16x4*)&Vt[headBase + (size_t)(ct * 16 + l16) * SS
                              + s0 + (wave >> 1) * 32 + q4 * 8 + (wave & 1) * 4] = pk;
            }
        }
    }
}

// ---------------------------------------------------------------------------
// Kernel 2: flash attention — byte-identical to R0 (measured best, 43.9us).
// ---------------------------------------------------------------------------
__global__ __launch_bounds__(512) void attn_kernel(
    const bf16_t* __restrict__ Qb, const bf16_t* __restrict__ Kb,
    const bf16_t* __restrict__ Vt, const int* __restrict__ mask,
    bf16_t* __restrict__ Og)
{
    __shared__ __align__(16) unsigned char smem[37376];
    auto Ks = (bf16_t(*)[64][72])(smem);            // [2][key][d]
    auto Vs = (bf16_t(*)[64][72])(smem + 18432);    // [2][d][kappa-key]
    auto Ms = (float(*)[64])(smem + 36864);         // [2][64] additive bias
    float* fbuf = (float*)smem;                      // combine: 32 KB
    float* lbuf = (float*)(smem + 32768);            // combine: 2 KB

    const int tid = threadIdx.x;
    const int w = tid >> 6, lane = tid & 63;
    const int q4 = lane >> 4, l16 = lane & 15;
    const int wq = w & 3, wk = w >> 2;
    const int qt = blockIdx.x, h = blockIdx.y, n = blockIdx.z;
    const size_t headBase = (size_t)(n * NHB + h) * SS * HS;
    const int* mrow = mask + n * SS;

    const int sr = tid >> 3, sc = (tid & 7) * 8;
    const bf16_t* kb_src = Kb + headBase + (size_t)sr * HS + sc;
    const bf16_t* vt_src = Vt + headBase + (size_t)sr * SS + sc;

    bf16x8 bq[2][2];
    #pragma unroll
    for (int st = 0; st < 2; ++st) {
        const bf16_t* qptr = Qb + headBase
            + (size_t)(qt * 128 + wq * 32 + st * 16 + l16) * HS;
        bq[st][0] = *(const bf16x8*)&qptr[q4 * 8];
        bq[st][1] = *(const bf16x8*)&qptr[32 + q4 * 8];
    }

    bf16x8 ones;
    #pragma unroll
    for (int i = 0; i < 8; ++i) ones[i] = (bf16_t)1.0f;

    f32x4 oaccT[2][4] = {};
    f32x4 lacc[2] = {};

    *(bf16x8*)&Ks[0][sr][sc] = *(const bf16x8*)kb_src;
    *(bf16x8*)&Vs[0][sr][sc] = *(const bf16x8*)vt_src;
    if (tid < 64) Ms[0][tid] = mrow[tid] ? 0.0f : -3e38f;
    __syncthreads();

    for (int kt = 0; kt < NT; ++kt) {
        const int cur = kt & 1;
        const bool has_next = (kt + 1) < NT;
        bf16x8 gk, gv; float gm = 0.f;
        if (has_next) {
            const int k0n = (kt + 1) * 64;
            gk = *(const bf16x8*)(kb_src + (size_t)k0n * HS);
            gv = *(const bf16x8*)(vt_src + k0n);
            if (tid < 64) gm = mrow[k0n + tid] ? 0.0f : -3e38f;
        }

        // S^T = bias + K.Q^T over this wave's 32-key half
        f32x4 sacc[2][2];
        #pragma unroll
        for (int c2 = 0; c2 < 2; ++c2) {
            const int ct = wk * 2 + c2;
            float4 bias = *(const float4*)&Ms[cur][ct * 16 + q4 * 4];
            f32x4 b4 = {bias.x, bias.y, bias.z, bias.w};
            sacc[0][c2] = b4; sacc[1][c2] = b4;
            bf16x8 ak0 = *(const bf16x8*)&Ks[cur][ct * 16 + l16][q4 * 8];
            bf16x8 ak1 = *(const bf16x8*)&Ks[cur][ct * 16 + l16][32 + q4 * 8];
            #pragma unroll
            for (int st = 0; st < 2; ++st) {
                sacc[st][c2] = mfma16(ak0, bq[st][0], sacc[st][c2]);
                sacc[st][c2] = mfma16(ak1, bq[st][1], sacc[st][c2]);
            }
        }

        // P = 2^S (Q carries log2e/32): one v_exp_f32 per element, no mul
        bf16x4 pv[2][2];
        #pragma unroll
        for (int c2 = 0; c2 < 2; ++c2)
            #pragma unroll
            for (int st = 0; st < 2; ++st) {
                bf16x4 pk;
                #pragma unroll
                for (int j = 0; j < 4; ++j)
                    pk[j] = (bf16_t)fast_exp2(sacc[st][c2][j]);
                pv[st][c2] = pk;
            }

        // O^T += V^T.P^T ; lsum += ones.P^T
        bf16x8 pa[2];
        #pragma unroll
        for (int st = 0; st < 2; ++st)
            pa[st] = __builtin_shufflevector(pv[st][0], pv[st][1],
                                             0, 1, 2, 3, 4, 5, 6, 7);
        #pragma unroll
        for (int dt = 0; dt < 4; ++dt) {
            bf16x8 av = *(const bf16x8*)&Vs[cur][dt * 16 + l16][wk * 32 + q4 * 8];
            oaccT[0][dt] = mfma16(av, pa[0], oaccT[0][dt]);
            oaccT[1][dt] = mfma16(av, pa[1], oaccT[1][dt]);
        }
        lacc[0] = mfma16(ones, pa[0], lacc[0]);
        lacc[1] = mfma16(ones, pa[1], lacc[1]);

        if (has_next) {
            const int nxt = 1 - cur;
            *(bf16x8*)&Ks[nxt][sr][sc] = gk;
            *(bf16x8*)&Vs[nxt][sr][sc] = gv;
            if (tid < 64) Ms[nxt][tid] = gm;
        }
        __syncthreads();
    }

    float ls[2] = {lacc[0][0], lacc[1][0]};

    // combine partner halves: waves 4-7 publish, waves 0-3 reduce + store
    if (w >= 4) {
        const int lanecol = wq * 64 + lane;
        #pragma unroll
        for (int st = 0; st < 2; ++st) {
            #pragma unroll
            for (int dt = 0; dt < 4; ++dt)
                #pragma unroll
                for (int j = 0; j < 4; ++j)
                    fbuf[(st * 16 + dt * 4 + j) * 256 + lanecol] = oaccT[st][dt][j];
            lbuf[st * 256 + lanecol] = ls[st];
        }
    }
    __syncthreads();
    if (w < 4) {
        const int lanecol = wq * 64 + lane;
        #pragma unroll
        for (int st = 0; st < 2; ++st) {
            #pragma unroll
            for (int dt = 0; dt < 4; ++dt)
                #pragma unroll
                for (int j = 0; j < 4; ++j)
                    oaccT[st][dt][j] += fbuf[(st * 16 + dt * 4 + j) * 256 + lanecol];
            ls[st] += lbuf[st * 256 + lanecol];
        }
        #pragma unroll
        for (int st = 0; st < 2; ++st) {
            const float inv = 1.f / ls[st];
            const int qrow = qt * 128 + wq * 32 + st * 16 + l16;
            bf16_t* obase = Og + ((size_t)(n * SS + qrow)) * EMB + h * HS;
            #pragma unroll
            for (int dt = 0; dt < 4; ++dt) {
                bf16x4 ov;
                #pragma unroll
                for (int j = 0; j < 4; ++j) ov[j] = (bf16_t)(oaccT[st][dt][j] * inv);
                *(bf16x4*)&obase[dt * 16 + q4 * 4] = ov;
            }
        }
    }
}

// ---------------------------------------------------------------------------
// Kernel 3: out = Og @ Wout.T + bout — byte-identical to R0 (measured-best).
// ---------------------------------------------------------------------------
__global__ __launch_bounds__(512) void outproj_kernel(
    const bf16_t* __restrict__ Og, const float* __restrict__ Wout,
    const float* __restrict__ bout, float* __restrict__ out)
{
    __shared__ bf16_t As[2][128][72];
    __shared__ bf16_t Bs[2][64][72];
    const int tid = threadIdx.x;
    const int w = tid >> 6, lane = tid & 63;
    const int q4 = lane >> 4, l16 = lane & 15;
    const int wr = w >> 1, wc = w & 1;
    const int t0 = blockIdx.x * 128, c0 = blockIdx.y * 64;

    const int sr0 = tid >> 3, sc0 = (tid & 7) * 8;
    const int sr1 = sr0 + 64;
    const bf16_t* a0 = Og + (size_t)(t0 + sr0) * EMB + sc0;
    const bf16_t* a1 = Og + (size_t)(t0 + sr1) * EMB + sc0;
    const float*  b0 = Wout + (size_t)(c0 + sr0) * EMB + sc0;

    auto cvt8 = [](float4 x, float4 y) {
        bf16x8 r;
        r[0] = (bf16_t)x.x; r[1] = (bf16_t)x.y; r[2] = (bf16_t)x.z; r[3] = (bf16_t)x.w;
        r[4] = (bf16_t)y.x; r[5] = (bf16_t)y.y; r[6] = (bf16_t)y.z; r[7] = (bf16_t)y.w;
        return r;
    };

    f32x4 acc[2][2] = {};

    *(bf16x8*)&As[0][sr0][sc0] = *(const bf16x8*)a0;
    *(bf16x8*)&As[0][sr1][sc0] = *(const bf16x8*)a1;
    *(bf16x8*)&Bs[0][sr0][sc0] = cvt8(*(const float4*)b0, *(const float4*)(b0 + 4));
    __syncthreads();

    const int NE = EMB / 64;
    for (int et = 0; et < NE; ++et) {
        const int cur = et & 1;
        const bool has_next = (et + 1) < NE;
        bf16x8 ga0, ga1; float4 gb0, gb1;
        if (has_next) {
            const int e0 = (et + 1) * 64;
            ga0 = *(const bf16x8*)(a0 + e0); ga1 = *(const bf16x8*)(a1 + e0);
            gb0 = *(const float4*)(b0 + e0); gb1 = *(const float4*)(b0 + e0 + 4);
        }

        bf16x8 af[2][2], bfr[2][2];
        #pragma unroll
        for (int st = 0; st < 2; ++st)
            #pragma unroll
            for (int kk = 0; kk < 2; ++kk)
                af[st][kk] = *(const bf16x8*)&As[cur][wr * 32 + st * 16 + l16][kk * 32 + q4 * 8];
        #pragma unroll
        for (int ct = 0; ct < 2; ++ct)
            #pragma unroll
            for (int kk = 0; kk < 2; ++kk)
                bfr[ct][kk] = *(const bf16x8*)&Bs[cur][wc * 32 + ct * 16 + l16][kk * 32 + q4 * 8];
        #pragma unroll
        for (int st = 0; st < 2; ++st)
            #pragma unroll
            for (int ct = 0; ct < 2; ++ct) {
                acc[st][ct] = mfma16(af[st][0], bfr[ct][0], acc[st][ct]);
                acc[st][ct] = mfma16(af[st][1], bfr[ct][1], acc[st][ct]);
            }

        if (has_next) {
            const int nxt = 1 - cur;
            *(bf16x8*)&As[nxt][sr0][sc0] = ga0;
            *(bf16x8*)&As[nxt][sr1][sc0] = ga1;
            *(bf16x8*)&Bs[nxt][sr0][sc0] = cvt8(gb0, gb1);
        }
        __syncthreads();
    }

    #pragma unroll
    for (int ct = 0; ct < 2; ++ct) {
        const int c = c0 + wc * 32 + ct * 16 + l16;
        const float bias = bout[c];
        #pragma unroll
        for (int st = 0; st < 2; ++st)
            #pragma unroll
            for (int i = 0; i < 4; ++i)
                out[(size_t)(t0 + wr * 32 + st * 16 + q4 * 4 + i) * EMB + c]
                    = acc[st][ct][i] + bias;
    }
}

extern "C" void kernel_launch(void* const* d_in, const int* in_sizes, int n_in,
                              void* d_out, int out_size, void* d_ws, size_t ws_size,
                              hipStream_t stream)
{
    const float* values  = (const float*)d_in[0];
    const float* keys    = (const float*)d_in[1];
    const float* queries = (const float*)d_in[2];
    const int*   mask    = (const int*)d_in[3];
    const float* Wq      = (const float*)d_in[4];
    const float* Wk      = (const float*)d_in[5];
    const float* Wv      = (const float*)d_in[6];
    const float* Wout    = (const float*)d_in[7];
    const float* bout    = (const float*)d_in[8];
    float* out = (float*)d_out;

    const size_t M8 = 8ull * 1024 * 1024;
    bf16_t* Qb = (bf16_t*)d_ws;
    bf16_t* Kb = (bf16_t*)((char*)d_ws + 1 * M8);
    bf16_t* Vt = (bf16_t*)((char*)d_ws + 2 * M8);
    bf16_t* Og = (bf16_t*)((char*)d_ws + 3 * M8);

    proj_kernel<<<dim3(SS / 128, NHB, BB), 512, 0, stream>>>(
        queries, keys, values, Wq, Wk, Wv, Qb, Kb, Vt);
    attn_kernel<<<dim3(SS / 128, NHB, BB), 512, 0, stream>>>(
        Qb, Kb, Vt, mask, Og);
    outproj_kernel<<<dim3((BB * SS) / 128, EMB / 64), 512, 0, stream>>>(
        Og, Wout, bout, out);
}